// Round 7
// baseline (221.309 us; speedup 1.0000x reference)
//
#include <hip/hip_runtime.h>

// LaplacianPyramidLoss: loss = sum_l mean(|pyr(x)[l] - pyr(t)[l]|)
// Linearity: pyr(x)-pyr(t) = pyr(x-t) -> ONE pyramid of d=x-t.
// R7: pure streaming, NO LDS / NO barriers. The 5x5 gaussian is exactly
// separable (k = g g^T with g = row sums, since sum(k)=T^2). Each WAVE
// independently processes a 128-col x 32-down-row strip: lanes hold 2 cols
// (float2), h-conv via 3 lane shuffles (+3 boundary patches), v-conv via a
// 5-row register ring, L1 term from the same registers, contiguous stores.
// One-step register prefetch + ~26 waves/CU gives the MLP that R6's
// barrier-lockstepped LDS pipeline could not (5 KB in flight vs 22 needed).
// Level 2 fuses the final mean(|down2|): down2 never touches HBM.

constexpr int THREADS = 256;
constexpr int DR = 32;    // down rows per wave chunk
constexpr int SW = 128;   // strip width in input cols (64 lanes x float2)

template <bool FUSE, bool LAST, bool WRITE_DOWN>
__global__ __launch_bounds__(THREADS)
void lap_stream(const float* __restrict__ A,   // x (lvl0) or cur
                const float* __restrict__ Bp,  // t (lvl0) or nullptr
                const float* __restrict__ w25, // 5x5 gaussian (channel 0)
                float* __restrict__ down,      // H/2 x W/2 (if WRITE_DOWN)
                float* __restrict__ sums,      // sums[level], sums[3] if LAST
                int H, int W, int strips, int chunks, int level)
{
    const int tid  = threadIdx.x;
    const int wv   = tid >> 6, lane = tid & 63;
    const int gw   = blockIdx.x * (THREADS / 64) + wv;  // global wave id
    const int spc  = strips * chunks;
    const int n    = gw / spc;                 // image-channel (B*C fused)
    const int rem  = gw - n * spc;
    const int strip = rem / chunks;
    const int chunk = rem - strip * chunks;

    // exact 1D factor: g_i = row-sum of w25 (k = g g^T since sum k = T^2)
    float g0, g1, g2, g3, g4;
    {
        float gg[5];
#pragma unroll
        for (int i = 0; i < 5; ++i) {
            float s = 0.f;
#pragma unroll
            for (int j = 0; j < 5; ++j) s += w25[i * 5 + j];
            gg[i] = s;
        }
        g0 = gg[0]; g1 = gg[1]; g2 = gg[2]; g3 = gg[3]; g4 = gg[4];
    }

    const int Hd = H >> 1, Wd = W >> 1;
    const int c0 = strip * SW;                 // input col base
    const int r0 = chunk * DR;                 // down row base
    const size_t ib = (size_t)n * H * W;
    const int cm = c0 + 2 * lane;              // this lane's 2 cols
    const int hc = (lane < 2) ? (c0 - 2 + lane) : (c0 + SW);  // halo col
    const bool hok = (lane < 3) && (hc >= 0) && (hc < W);

    // load one input row: d = (x-t) or cur at cols (cm, cm+1); dh = halo col
    auto loadrow = [&](int gy, float2& d, float& dh) {
        d = make_float2(0.f, 0.f); dh = 0.f;   // vertical zero-pad
        if ((unsigned)gy < (unsigned)H) {      // wave-uniform branch
            const float* ra = A + ib + (size_t)gy * W;
            d = *(const float2*)(ra + cm);
            float h = hok ? ra[hc] : 0.f;      // horizontal zero-pad via hok
            if (FUSE) {
                const float* rt = Bp + ib + (size_t)gy * W;
                const float2 t2 = *(const float2*)(rt + cm);
                d.x -= t2.x; d.y -= t2.y;
                if (hok) h -= rt[hc];
            }
            dh = h;
        }
    };

    // horizontal 5-tap at this lane's EVEN col (cm): needs cols cm-2..cm+2
    auto hconv = [&](const float2 d, const float dh) -> float {
        float dm2 = __shfl(d.x, lane - 1);     // col cm-2 (wraps lane0 -> patched)
        float dm1 = __shfl(d.y, lane - 1);     // col cm-1
        float dp2 = __shfl(d.x, lane + 1);     // col cm+2 (wraps lane63 -> patched)
        const float hl0 = __shfl(dh, 0);       // col c0-2
        const float hl1 = __shfl(dh, 1);       // col c0-1
        const float hr0 = __shfl(dh, 2);       // col c0+128
        if (lane == 0)  { dm2 = hl0; dm1 = hl1; }
        if (lane == 63) { dp2 = hr0; }
        float h = g0 * dm2;
        h = fmaf(g1, dm1, h);
        h = fmaf(g2, d.x, h);
        h = fmaf(g3, d.y, h);
        h = fmaf(g4, dp2, h);
        return h;
    };

    // ---- prologue: h ring for rows 2r0-2, 2r0-1, 2r0; keep d[2r0] ----
    float2 dt; float et;
    loadrow(2 * r0 - 2, dt, et); float hA = hconv(dt, et);
    loadrow(2 * r0 - 1, dt, et); float hB = hconv(dt, et);
    float2 dP;                                  // d row 2r (for L1 term)
    loadrow(2 * r0,     dP, et); float hC = hconv(dP, et);

    // one-step register prefetch (double-buffered, static indices via unroll)
    float2 d1[2], d2[2]; float e1[2], e2[2];
    loadrow(2 * r0 + 1, d1[0], e1[0]);
    loadrow(2 * r0 + 2, d2[0], e2[0]);

    float lsum = 0.f, dsum = 0.f;
#pragma unroll 2
    for (int s = 0; s < DR; ++s) {
        const int cb = s & 1, nb = cb ^ 1;      // compile-time after unroll 2
        if (s + 1 < DR) {                       // issue next step's loads first
            loadrow(2 * (r0 + s) + 3, d1[nb], e1[nb]);
            loadrow(2 * (r0 + s) + 4, d2[nb], e2[nb]);
        }
        const float hD = hconv(d1[cb], e1[cb]); // h[2r+1]
        const float hE = hconv(d2[cb], e2[cb]); // h[2r+2]
        float acc = g0 * hA;                    // v-conv -> down[r][cm/2]
        acc = fmaf(g1, hB, acc);
        acc = fmaf(g2, hC, acc);
        acc = fmaf(g3, hD, acc);
        acc = fmaf(g4, hE, acc);
        if (WRITE_DOWN)                         // 64 contiguous dwords/wave
            down[(size_t)n * Hd * Wd + (size_t)(r0 + s) * Wd + (c0 >> 1) + lane] = acc;
        // lap = cur - up(down): rows 2r,2r+1 x cols cm,cm+1 all map to acc
        lsum += fabsf(dP.x - acc) + fabsf(dP.y - acc)
              + fabsf(d1[cb].x - acc) + fabsf(d1[cb].y - acc);
        if (LAST) dsum += fabsf(acc);
        hA = hC; hB = hD; hC = hE; dP = d2[cb]; // roll the rings
    }

    // ---- wave reduce -> block reduce -> one atomic per level ----
#pragma unroll
    for (int off = 32; off > 0; off >>= 1) {
        lsum += __shfl_down(lsum, off);
        if (LAST) dsum += __shfl_down(dsum, off);
    }
    __shared__ float wsl[THREADS / 64], wsd[THREADS / 64];
    if (lane == 0) { wsl[wv] = lsum; if (LAST) wsd[wv] = dsum; }
    __syncthreads();
    if (tid == 0) {
        atomicAdd(&sums[level], wsl[0] + wsl[1] + wsl[2] + wsl[3]);
        if (LAST) atomicAdd(&sums[3], wsd[0] + wsd[1] + wsd[2] + wsd[3]);
    }
}

__global__ void finalize_kernel(const float* __restrict__ sums,
                                float* __restrict__ out,
                                float inv0, float inv1, float inv2, float inv3)
{
    out[0] = sums[0] * inv0 + sums[1] * inv1 + sums[2] * inv2 + sums[3] * inv3;
}

extern "C" void kernel_launch(void* const* d_in, const int* in_sizes, int n_in,
                              void* d_out, int out_size, void* d_ws, size_t ws_size,
                              hipStream_t stream)
{
    const float* x   = (const float*)d_in[0];
    const float* t   = (const float*)d_in[1];
    const float* ker = (const float*)d_in[2];  // (13,1,5,5); channels identical
    float* out = (float*)d_out;

    constexpr int B = 16, C = 13, H = 512, W = 512;
    constexpr int N = B * C;  // 208 image-channels

    // ws: [256B sums] [down0: N*256*256 f32] [down1: N*128*128 f32]
    float* sums  = (float*)d_ws;
    float* down0 = (float*)((char*)d_ws + 256);
    float* down1 = down0 + (size_t)N * (H / 2) * (W / 2);

    hipMemsetAsync(sums, 0, 4 * sizeof(float), stream);

    dim3 blk(THREADS);
    // level 0: 512x512, FUSE d=x-t. strips=512/128=4, chunks=256/32=8
    {
        const int strips = W / SW, chunks = (H / 2) / DR;
        const int blocks = N * strips * chunks / (THREADS / 64);  // 1664
        lap_stream<true, false, true><<<blocks, blk, 0, stream>>>(
            x, t, ker, down0, sums, H, W, strips, chunks, 0);
    }
    // level 1: 256x256. strips=2, chunks=4
    {
        const int strips = (W/2) / SW, chunks = (H / 4) / DR;
        const int blocks = N * strips * chunks / (THREADS / 64);  // 416
        lap_stream<false, false, true><<<blocks, blk, 0, stream>>>(
            down0, nullptr, ker, down1, sums, H / 2, W / 2, strips, chunks, 1);
    }
    // level 2: 128x128, LAST (fuses mean|down2|, no down write). strips=1, chunks=2
    {
        const int strips = (W/4) / SW, chunks = (H / 8) / DR;
        const int blocks = N * strips * chunks / (THREADS / 64);  // 104
        lap_stream<false, true, false><<<blocks, blk, 0, stream>>>(
            down1, nullptr, ker, nullptr, sums, H / 4, W / 4, strips, chunks, 2);
    }

    const float inv0 = 1.0f / ((float)N * H * W);
    const float inv1 = 1.0f / ((float)N * (H/2) * (W/2));
    const float inv2 = 1.0f / ((float)N * (H/4) * (W/4));
    const float inv3 = 1.0f / ((float)N * (H/8) * (W/8));
    finalize_kernel<<<1, 1, 0, stream>>>(sums, out, inv0, inv1, inv2, inv3);
}